// Round 5
// baseline (250.813 us; speedup 1.0000x reference)
//
#include <hip/hip_runtime.h>
#include <hip/hip_fp16.h>

#define NEG_SLOPE 0.01f
#define RANGE_BITS 14
#define RANGE (1 << RANGE_BITS)     // 16384 nodes per histogram range (64 KB LDS)
#define SLICE_BITS 16
#define SLICE (1 << SLICE_BITS)     // 65536 edges per slice

typedef _Float16 half2_t __attribute__((ext_vector_type(2)));

__device__ __forceinline__ float lrelu(float x) { return x > 0.f ? x : NEG_SLOPE * x; }

__device__ __forceinline__ unsigned pack2h(float a, float b) {
    __half2 h = __floats2half2_rn(a, b);
    unsigned u; __builtin_memcpy(&u, &h, 4); return u;
}
__device__ __forceinline__ half2_t uh(unsigned u) {
    half2_t r; __builtin_memcpy(&r, &u, 4); return r;
}
__device__ __forceinline__ float2 unpack2(unsigned u) {
    __half2 h = *reinterpret_cast<__half2*>(&u);
    return __half22float2(h);
}

#if __has_builtin(__builtin_amdgcn_fdot2)
__device__ __forceinline__ float fdot2(unsigned a, unsigned b, float c) {
    return __builtin_amdgcn_fdot2(uh(a), uh(b), c, false);
}
#else
__device__ __forceinline__ float fdot2(unsigned a, unsigned b, float c) {
    half2_t ha = uh(a), hb = uh(b);
    return c + (float)ha[0] * (float)hb[0] + (float)ha[1] * (float)hb[1];
}
#endif

// ---------------- pass A: per-(array,range,slice) LDS histogram ----------------
__global__ __launch_bounds__(1024) void count_kernel(
    const int* __restrict__ snd, const int* __restrict__ rcv,
    int* __restrict__ partial, int* __restrict__ pos_local,
    int nE, int NR, int NS)
{
    __shared__ int hist[RANGE];
    const int b = blockIdx.x;
    const int a = b / (NR * NS);
    const int rem = b - a * NR * NS;
    const int r = rem / NS;
    const int s = rem - r * NS;
    const int t = threadIdx.x;
    for (int k = t; k < RANGE; k += 1024) hist[k] = 0;
    __syncthreads();
    const int base = r << RANGE_BITS;
    const int lo = s << SLICE_BITS;
    const int hi = min(lo + SLICE, nE);
    if (a == 0) {
        for (int i = lo + t; i < hi; i += 1024) {
            const int v = rcv[i];
            const unsigned d = (unsigned)(v - base);
            if (d < (unsigned)RANGE) {
                const int lp = atomicAdd(&hist[d], 1);
                pos_local[i] = lp;
            }
        }
    } else {
        for (int i = lo + t; i < hi; i += 1024) {
            const int v = snd[i];
            const unsigned d = (unsigned)(v - base);
            if (d < (unsigned)RANGE) atomicAdd(&hist[d], 1);
        }
    }
    __syncthreads();
    int* dst = partial + (size_t)((a * NR + r) * NS + s) * RANGE;
    for (int k = t; k < RANGE; k += 1024) dst[k] = hist[k];
}

// ---------------- pass B: scan rcv partials over slices, degrees, rin/rout ----------------
__global__ __launch_bounds__(256) void scanp_kernel(
    int* __restrict__ partial,
    int* __restrict__ dr_i,
    float* __restrict__ rin, float* __restrict__ rout,
    int nN, int NR, int NS)
{
    const int gid = blockIdx.x * 256 + threadIdx.x;
    if (gid >= (NR << RANGE_BITS)) return;
    const int r = gid >> RANGE_BITS;
    const int node = gid & (RANGE - 1);
    int* prcv = partial + (size_t)(r * NS) * RANGE + node;
    int run = 0;
    for (int s = 0; s < NS; ++s) {
        int* p = prcv + (size_t)s * RANGE;
        const int c = *p;
        *p = run;
        run += c;
    }
    const int* psnd = partial + (size_t)((NR + r) * NS) * RANGE + node;
    int tot = 0;
    for (int s = 0; s < NS; ++s) tot += psnd[(size_t)s * RANGE];
    if (gid < nN) {
        dr_i[gid] = run;
        rout[gid] = rsqrtf(fmaxf((float)run, 1.f));
        rin[gid]  = rsqrtf(fmaxf((float)tot, 1.f));
    }
}

// ---------------- scan stage 1 ----------------
__global__ __launch_bounds__(256) void scan1_kernel(const int* __restrict__ cnt,
                                                    int* __restrict__ rowptr,
                                                    int* __restrict__ bsums, int n)
{
    __shared__ int sd[256];
    const int t = threadIdx.x;
    const int base = blockIdx.x * 1024 + t * 4;
    int v0 = (base + 0 < n) ? cnt[base + 0] : 0;
    int v1 = (base + 1 < n) ? cnt[base + 1] : 0;
    int v2 = (base + 2 < n) ? cnt[base + 2] : 0;
    int v3 = (base + 3 < n) ? cnt[base + 3] : 0;
    const int p1 = v0, p2 = v0 + v1, p3 = v0 + v1 + v2;
    const int tot = p3 + v3;
    sd[t] = tot;
    __syncthreads();
    for (int off = 1; off < 256; off <<= 1) {
        int y = (t >= off) ? sd[t - off] : 0;
        __syncthreads();
        sd[t] += y;
        __syncthreads();
    }
    const int excl = sd[t] - tot;
    if (base + 0 < n) rowptr[base + 0] = excl;
    if (base + 1 < n) rowptr[base + 1] = excl + p1;
    if (base + 2 < n) rowptr[base + 2] = excl + p2;
    if (base + 3 < n) rowptr[base + 3] = excl + p3;
    if (t == 255) bsums[blockIdx.x] = sd[255];
}

// ---------------- scan stage 2 ----------------
__global__ __launch_bounds__(256) void scan2_kernel(int* __restrict__ bsums, int nb)
{
    __shared__ int sd[256];
    const int t = threadIdx.x;
    const int v = (t < nb) ? bsums[t] : 0;
    sd[t] = v;
    __syncthreads();
    for (int off = 1; off < 256; off <<= 1) {
        int y = (t >= off) ? sd[t - off] : 0;
        __syncthreads();
        sd[t] += y;
        __syncthreads();
    }
    if (t < nb) bsums[t] = sd[t] - v;
}

// ---------------- scan stage 3 ----------------
__global__ __launch_bounds__(256) void scan3_kernel(int* __restrict__ rowptr,
                                                    const int* __restrict__ bsums,
                                                    int n, int nE)
{
    const int gid = blockIdx.x * 256 + threadIdx.x;
    if (gid < n) rowptr[gid] += bsums[gid >> 10];
    if (gid == 0) rowptr[n] = nE;
}

// ---------------- pass C: atomic-free CSR fill ----------------
__global__ __launch_bounds__(256) void fill_kernel(
    const int* __restrict__ snd, const int* __restrict__ rcv,
    const int* __restrict__ pos_local, const int* __restrict__ partial,
    const int* __restrict__ rowptr, int* __restrict__ csr_src,
    int nE, int NS)
{
    const int i = blockIdx.x * 256 + threadIdx.x;
    if (i >= nE) return;
    const int rv = rcv[i];
    const int r = rv >> RANGE_BITS;
    const int s = i >> SLICE_BITS;
    const int pref = partial[(size_t)(r * NS + s) * RANGE + (rv & (RANGE - 1))];
    const int pos = rowptr[rv] + pref + pos_local[i];
    csr_src[pos] = snd[i];
}

// ---------------- fused MLP + W3 projection (fp16 dot2, f32 accumulate):
// p = fp16( rin * ( lrelu(lrelu(X@W1+b1)@W2+b2) @ W3 ) )   [N,40]
// 128 rows/block, 256 threads, 8x4 micro-tile, 5 barriers.
__global__ __launch_bounds__(256, 3) void mlp_kernel(
    const float* __restrict__ X, const float* __restrict__ W1, const float* __restrict__ b1,
    const float* __restrict__ W2, const float* __restrict__ b2, const float* __restrict__ W3,
    const float* __restrict__ rin, __half* __restrict__ p, int nN)
{
    // regionA: Xs2 [64 k2][128 rows]  (32768 u32... 8192 u32)
    //          -> H2s [32 c2][132]    (4224 u32)
    //          -> h2  [128 rows][66]  (8448 u32)
    __shared__ unsigned regionA[8448];          // 33792 B
    // regionW: W1c2 [64 k2][68]       (4352 u32)
    //          -> W2c2 [32][68] (2176) + W3c2 [32][44] (1408)
    __shared__ unsigned regionW[4352];          // 17408 B
    unsigned* Xs2  = regionA;                   // stride 128
    unsigned* H2s  = regionA;                   // stride 132
    unsigned* h2s  = regionA;                   // stride 66
    unsigned* W1c2 = regionW;                   // stride 68
    unsigned* W2c2 = regionW;                   // stride 68
    unsigned* W3c2 = regionW + 2176;            // stride 44

    const int t = threadIdx.x;
    const int row0 = blockIdx.x * 128;

    // ---- stage X (f32 -> packed half2, [k2][row]) ----
    {
        const int w = t >> 6, lane = t & 63;
        const int rloc = (w & 1) * 64 + lane;
        const int grow = row0 + rloc;
        const bool rv = grow < nN;
        const float4* Xrow = (const float4*)(X + (size_t)grow * 128);
        const int k4b = (w >> 1) * 16;
#pragma unroll 4
        for (int it = 0; it < 16; ++it) {
            const int k4 = k4b + it;
            float4 v = rv ? Xrow[k4] : make_float4(0.f, 0.f, 0.f, 0.f);
            Xs2[(2 * k4)     * 128 + rloc] = pack2h(v.x, v.y);
            Xs2[(2 * k4 + 1) * 128 + rloc] = pack2h(v.z, v.w);
        }
        // stage W1 pairs [k2][c]
        const int c = t & 63;
        const int k2b = t >> 6;
#pragma unroll 4
        for (int it = 0; it < 16; ++it) {
            const int k2 = k2b + 4 * it;
            W1c2[k2 * 68 + c] = pack2h(W1[(2 * k2) * 64 + c], W1[(2 * k2 + 1) * 64 + c]);
        }
    }
    __syncthreads();

    const int ty = t >> 4;       // 0..15 -> 8 rows each
    const int tx = t & 15;       // 0..15 -> 4 cols each
    const float4 bias1 = *(const float4*)&b1[4 * tx];
    const float4 bias2 = *(const float4*)&b2[4 * tx];

    // ---- GEMM1: h1 = lrelu(X@W1+b1), K=128 (64 pairs) ----
    float acc[8][4];
#pragma unroll
    for (int i = 0; i < 8; ++i)
#pragma unroll
        for (int j = 0; j < 4; ++j) acc[i][j] = 0.f;

    {
        const unsigned* aBase = Xs2 + 8 * ty;
        const unsigned* bBase = W1c2 + 4 * tx;
#pragma unroll 2
        for (int k2 = 0; k2 < 64; ++k2) {
            const uint4 a0 = *(const uint4*)(aBase + k2 * 128);
            const uint4 a1 = *(const uint4*)(aBase + k2 * 128 + 4);
            const uint4 bb = *(const uint4*)(bBase + k2 * 68);
            const unsigned av[8] = {a0.x, a0.y, a0.z, a0.w, a1.x, a1.y, a1.z, a1.w};
            const unsigned bv[4] = {bb.x, bb.y, bb.z, bb.w};
#pragma unroll
            for (int i = 0; i < 8; ++i)
#pragma unroll
                for (int j = 0; j < 4; ++j)
                    acc[i][j] = fdot2(av[i], bv[j], acc[i][j]);
        }
    }
    __syncthreads();   // Xs2/W1c2 dead

    // ---- h1 -> H2s pairs-along-col [c2][row]; stage W2/W3 ----
#pragma unroll
    for (int i = 0; i < 8; ++i) {
        const int row = 8 * ty + i;
        const float g0 = lrelu(acc[i][0] + bias1.x);
        const float g1 = lrelu(acc[i][1] + bias1.y);
        const float g2 = lrelu(acc[i][2] + bias1.z);
        const float g3 = lrelu(acc[i][3] + bias1.w);
        H2s[(2 * tx)     * 132 + row] = pack2h(g0, g1);
        H2s[(2 * tx + 1) * 132 + row] = pack2h(g2, g3);
    }
    {
        const int c = t & 63;
        const int k2b = t >> 6;
#pragma unroll 2
        for (int it = 0; it < 8; ++it) {
            const int k2 = k2b + 4 * it;
            W2c2[k2 * 68 + c] = pack2h(W2[(2 * k2) * 64 + c], W2[(2 * k2 + 1) * 64 + c]);
        }
        if (c < 40) {
#pragma unroll 2
            for (int it = 0; it < 8; ++it) {
                const int k2 = k2b + 4 * it;
                W3c2[k2 * 44 + c] = pack2h(W3[(2 * k2) * 40 + c], W3[(2 * k2 + 1) * 40 + c]);
            }
        }
    }
    __syncthreads();

    // ---- GEMM2: h2 = lrelu(h1@W2+b2), K=64 (32 pairs) ----
#pragma unroll
    for (int i = 0; i < 8; ++i)
#pragma unroll
        for (int j = 0; j < 4; ++j) acc[i][j] = 0.f;
    {
        const unsigned* aBase = H2s + 8 * ty;
        const unsigned* bBase = W2c2 + 4 * tx;
#pragma unroll 2
        for (int k2 = 0; k2 < 32; ++k2) {
            const uint4 a0 = *(const uint4*)(aBase + k2 * 132);
            const uint4 a1 = *(const uint4*)(aBase + k2 * 132 + 4);
            const uint4 bb = *(const uint4*)(bBase + k2 * 68);
            const unsigned av[8] = {a0.x, a0.y, a0.z, a0.w, a1.x, a1.y, a1.z, a1.w};
            const unsigned bv[4] = {bb.x, bb.y, bb.z, bb.w};
#pragma unroll
            for (int i = 0; i < 8; ++i)
#pragma unroll
                for (int j = 0; j < 4; ++j)
                    acc[i][j] = fdot2(av[i], bv[j], acc[i][j]);
        }
    }
    __syncthreads();   // H2s dead

    // ---- h2 -> [row][k2] pairs-along-k ----
#pragma unroll
    for (int i = 0; i < 8; ++i) {
        const int row = 8 * ty + i;
        const float g0 = lrelu(acc[i][0] + bias2.x);
        const float g1 = lrelu(acc[i][1] + bias2.y);
        const float g2 = lrelu(acc[i][2] + bias2.z);
        const float g3 = lrelu(acc[i][3] + bias2.w);
        h2s[row * 66 + 2 * tx]     = pack2h(g0, g1);
        h2s[row * 66 + 2 * tx + 1] = pack2h(g2, g3);
    }
    __syncthreads();

    // ---- projection: p = rin * (h2 @ W3), 2 rows x 10 cols per thread ----
    {
        const int cseg = t & 3;          // 10 cols each
        const int rr   = t >> 2;         // rows rr, rr+64
        float pa[2][10];
#pragma unroll
        for (int r = 0; r < 2; ++r)
#pragma unroll
            for (int j = 0; j < 10; ++j) pa[r][j] = 0.f;

        for (int k2 = 0; k2 < 32; ++k2) {
            const unsigned a0 = h2s[rr * 66 + k2];
            const unsigned a1 = h2s[(rr + 64) * 66 + k2];
            const uint2* w2p = (const uint2*)(W3c2 + k2 * 44 + cseg * 10);
            unsigned wv[10];
#pragma unroll
            for (int m = 0; m < 5; ++m) {
                const uint2 ww = w2p[m];
                wv[2 * m] = ww.x; wv[2 * m + 1] = ww.y;
            }
#pragma unroll
            for (int j = 0; j < 10; ++j) {
                pa[0][j] = fdot2(a0, wv[j], pa[0][j]);
                pa[1][j] = fdot2(a1, wv[j], pa[1][j]);
            }
        }
#pragma unroll
        for (int r = 0; r < 2; ++r) {
            const int grow = row0 + rr + r * 64;
            if (grow < nN) {
                const float rs = rin[grow];
                unsigned* pr = (unsigned*)(p + (size_t)grow * 40) + cseg * 5;
#pragma unroll
                for (int m = 0; m < 5; ++m)
                    pr[m] = pack2h(pa[r][2 * m] * rs, pa[r][2 * m + 1] * rs);
            }
        }
    }
}

// ---------------- agg1 (fp16 CSR gather): q = rin*rout * sum p[src]; c = rout * sum rin[src]
__global__ __launch_bounds__(256) void agg1_kernel(const __half* __restrict__ p,
                                                   const int* __restrict__ csr_src,
                                                   const int* __restrict__ rowptr,
                                                   const float* __restrict__ rin,
                                                   const float* __restrict__ rout,
                                                   __half* __restrict__ qbuf,
                                                   float* __restrict__ cbuf, int nN)
{
    const int gid = blockIdx.x * 256 + threadIdx.x;
    const int node = gid >> 2;
    const int q4 = gid & 3;
    if (node >= nN) return;
    const int beg = rowptr[node], end = rowptr[node + 1];
    const bool has2 = (q4 == 1);       // lane 1 also owns chunk 4; lane 0 owns rin-sum
    float a[16];
#pragma unroll
    for (int j = 0; j < 16; ++j) a[j] = 0.f;
    float cs = 0.f;
    for (int e = beg; e < end; ++e) {
        const int src = csr_src[e];
        const uint4* row = (const uint4*)(p + (size_t)src * 40);
        const uint4 u = row[q4];
        float2 f;
        f = unpack2(u.x); a[0] += f.x; a[1] += f.y;
        f = unpack2(u.y); a[2] += f.x; a[3] += f.y;
        f = unpack2(u.z); a[4] += f.x; a[5] += f.y;
        f = unpack2(u.w); a[6] += f.x; a[7] += f.y;
        if (has2) {
            const uint4 v = row[4];
            f = unpack2(v.x); a[8]  += f.x; a[9]  += f.y;
            f = unpack2(v.y); a[10] += f.x; a[11] += f.y;
            f = unpack2(v.z); a[12] += f.x; a[13] += f.y;
            f = unpack2(v.w); a[14] += f.x; a[15] += f.y;
        }
        if (q4 == 0) cs += rin[src];
    }
    const float sc = rin[node] * rout[node];
    uint4 o;
    o.x = pack2h(a[0] * sc, a[1] * sc);
    o.y = pack2h(a[2] * sc, a[3] * sc);
    o.z = pack2h(a[4] * sc, a[5] * sc);
    o.w = pack2h(a[6] * sc, a[7] * sc);
    uint4* qr = (uint4*)(qbuf + (size_t)node * 40);
    qr[q4] = o;
    if (has2) {
        uint4 o2;
        o2.x = pack2h(a[8]  * sc, a[9]  * sc);
        o2.y = pack2h(a[10] * sc, a[11] * sc);
        o2.z = pack2h(a[12] * sc, a[13] * sc);
        o2.w = pack2h(a[14] * sc, a[15] * sc);
        qr[4] = o2;
    }
    if (q4 == 0) cbuf[node] = cs * rout[node];
}

// ---------------- agg2 + bias-term + softmax -> out (f32) ----------------
__global__ __launch_bounds__(256) void agg2_kernel(const __half* __restrict__ qbuf,
                                                   const int* __restrict__ csr_src,
                                                   const int* __restrict__ rowptr,
                                                   const float* __restrict__ rout,
                                                   const float* __restrict__ cbuf,
                                                   const float* __restrict__ b3,
                                                   float* __restrict__ out, int nN)
{
    const int gid = blockIdx.x * 256 + threadIdx.x;
    const int node = gid >> 2;
    const int q4 = gid & 3;
    if (node >= nN) return;
    const int beg = rowptr[node], end = rowptr[node + 1];
    const bool has2 = (q4 == 1);
    float a[16];
#pragma unroll
    for (int j = 0; j < 16; ++j) a[j] = 0.f;
    for (int e = beg; e < end; ++e) {
        const int src = csr_src[e];
        const uint4* row = (const uint4*)(qbuf + (size_t)src * 40);
        const uint4 u = row[q4];
        float2 f;
        f = unpack2(u.x); a[0] += f.x; a[1] += f.y;
        f = unpack2(u.y); a[2] += f.x; a[3] += f.y;
        f = unpack2(u.z); a[4] += f.x; a[5] += f.y;
        f = unpack2(u.w); a[6] += f.x; a[7] += f.y;
        if (has2) {
            const uint4 v = row[4];
            f = unpack2(v.x); a[8]  += f.x; a[9]  += f.y;
            f = unpack2(v.y); a[10] += f.x; a[11] += f.y;
            f = unpack2(v.z); a[12] += f.x; a[13] += f.y;
            f = unpack2(v.w); a[14] += f.x; a[15] += f.y;
        }
    }
    const float ro = rout[node];
    const float c  = cbuf[node];
    float z[16];
#pragma unroll
    for (int j = 0; j < 8; ++j) z[j] = ro * a[j] + c * b3[q4 * 8 + j];
    if (has2) {
#pragma unroll
        for (int j = 0; j < 8; ++j) z[8 + j] = ro * a[8 + j] + c * b3[32 + j];
    }
    float m = z[0];
#pragma unroll
    for (int j = 1; j < 8; ++j) m = fmaxf(m, z[j]);
    if (has2) {
#pragma unroll
        for (int j = 8; j < 16; ++j) m = fmaxf(m, z[j]);
    }
    m = fmaxf(m, __shfl_xor(m, 1));
    m = fmaxf(m, __shfl_xor(m, 2));
    float s = 0.f;
#pragma unroll
    for (int j = 0; j < 8; ++j) { z[j] = __expf(z[j] - m); s += z[j]; }
    if (has2) {
#pragma unroll
        for (int j = 8; j < 16; ++j) { z[j] = __expf(z[j] - m); s += z[j]; }
    }
    s += __shfl_xor(s, 1);
    s += __shfl_xor(s, 2);
    const float inv = 1.f / s;
    float4* orow = (float4*)(out + (size_t)node * 40);
    orow[q4 * 2 + 0] = make_float4(z[0] * inv, z[1] * inv, z[2] * inv, z[3] * inv);
    orow[q4 * 2 + 1] = make_float4(z[4] * inv, z[5] * inv, z[6] * inv, z[7] * inv);
    if (has2) {
        orow[8] = make_float4(z[8]  * inv, z[9]  * inv, z[10] * inv, z[11] * inv);
        orow[9] = make_float4(z[12] * inv, z[13] * inv, z[14] * inv, z[15] * inv);
    }
}

extern "C" void kernel_launch(void* const* d_in, const int* in_sizes, int n_in,
                              void* d_out, int out_size, void* d_ws, size_t ws_size,
                              hipStream_t stream)
{
    const float* nodes = (const float*)d_in[0];
    const int*   snd   = (const int*)d_in[1];
    const int*   rcv   = (const int*)d_in[2];
    const float* W1    = (const float*)d_in[3];
    const float* b1    = (const float*)d_in[4];
    const float* W2    = (const float*)d_in[5];
    const float* b2    = (const float*)d_in[6];
    const float* W3    = (const float*)d_in[7];
    const float* b3    = (const float*)d_in[8];

    const int nN = in_sizes[0] / 128;
    const int nE = in_sizes[1];
    const int NR = (nN + RANGE - 1) >> RANGE_BITS;   // 7 for N=100000
    const int NS = (nE + SLICE - 1) >> SLICE_BITS;   // 25 for E=1.6M

    size_t off = 0;
    auto alloc = [&](size_t n) { size_t r = off; off += (n + 3) & ~(size_t)3; return r; };
    int*   dr_i    = (int*)d_ws + alloc(nN);
    int*   rowptr  = (int*)d_ws + alloc(nN + 1);
    int*   bsums   = (int*)d_ws + alloc(256);
    float* rin     = (float*)d_ws + alloc(nN);
    float* rout    = (float*)d_ws + alloc(nN);
    float* cbuf    = (float*)d_ws + alloc(nN);
    int*   csr_src = (int*)d_ws + alloc(nE);
    // union region: {partial + pos_local} (dead after fill) overlaps {pbuf + qbuf} (fp16)
    const size_t psz = (size_t)2 * NR * NS * RANGE;
    size_t ubase = alloc(0);
    int*    partial   = (int*)d_ws + ubase;
    int*    pos_local = (int*)d_ws + ubase + psz;
    __half* pbuf      = (__half*)((int*)d_ws + ubase);
    __half* qbuf      = pbuf + (size_t)nN * 40;     // byte offset nN*80, 16B-aligned

    const int nb1 = (nN + 1023) / 1024;

    count_kernel<<<2 * NR * NS, 1024, 0, stream>>>(snd, rcv, partial, pos_local, nE, NR, NS);
    scanp_kernel<<<(NR * RANGE + 255) / 256, 256, 0, stream>>>(partial, dr_i, rin, rout, nN, NR, NS);
    scan1_kernel<<<nb1, 256, 0, stream>>>(dr_i, rowptr, bsums, nN);
    scan2_kernel<<<1, 256, 0, stream>>>(bsums, nb1);
    scan3_kernel<<<(nN + 255) / 256, 256, 0, stream>>>(rowptr, bsums, nN, nE);
    fill_kernel<<<(nE + 255) / 256, 256, 0, stream>>>(snd, rcv, pos_local, partial, rowptr, csr_src, nE, NS);
    mlp_kernel<<<(nN + 127) / 128, 256, 0, stream>>>(nodes, W1, b1, W2, b2, W3, rin, pbuf, nN);
    agg1_kernel<<<((size_t)nN * 4 + 255) / 256, 256, 0, stream>>>(pbuf, csr_src, rowptr, rin, rout, qbuf, cbuf, nN);
    agg2_kernel<<<((size_t)nN * 4 + 255) / 256, 256, 0, stream>>>(qbuf, csr_src, rowptr, rout, cbuf, b3, (float*)d_out, nN);
}

// Round 6
// 214.441 us; speedup vs baseline: 1.1696x; 1.1696x over previous
//
#include <hip/hip_runtime.h>
#include <hip/hip_fp16.h>

#define NEG_SLOPE 0.01f
#define RANGE_BITS 14
#define RANGE (1 << RANGE_BITS)     // 16384 nodes per histogram range (64 KB LDS)
#define SLICE_BITS 16
#define SLICE (1 << SLICE_BITS)     // 65536 edges per slice

typedef _Float16 f16x8 __attribute__((ext_vector_type(8)));
typedef float f32x4 __attribute__((ext_vector_type(4)));

__device__ __forceinline__ float lrelu(float x) { return x > 0.f ? x : NEG_SLOPE * x; }

__device__ __forceinline__ unsigned pack2h(float a, float b) {
    __half2 h = __floats2half2_rn(a, b);
    unsigned u; __builtin_memcpy(&u, &h, 4); return u;
}
__device__ __forceinline__ float2 unpack2(unsigned u) {
    __half2 h = *reinterpret_cast<__half2*>(&u);
    return __half22float2(h);
}
__device__ __forceinline__ f16x8 u4h8(uint4 u) {
    f16x8 r; __builtin_memcpy(&r, &u, 16); return r;
}

// ---------------- pass A: per-(array,range,slice) LDS histogram ----------------
__global__ __launch_bounds__(1024) void count_kernel(
    const int* __restrict__ snd, const int* __restrict__ rcv,
    int* __restrict__ partial, int* __restrict__ pos_local,
    int nE, int NR, int NS)
{
    __shared__ int hist[RANGE];
    const int b = blockIdx.x;
    const int a = b / (NR * NS);
    const int rem = b - a * NR * NS;
    const int r = rem / NS;
    const int s = rem - r * NS;
    const int t = threadIdx.x;
    for (int k = t; k < RANGE; k += 1024) hist[k] = 0;
    __syncthreads();
    const int base = r << RANGE_BITS;
    const int lo = s << SLICE_BITS;
    const int hi = min(lo + SLICE, nE);
    if (a == 0) {
        for (int i = lo + t; i < hi; i += 1024) {
            const int v = rcv[i];
            const unsigned d = (unsigned)(v - base);
            if (d < (unsigned)RANGE) {
                const int lp = atomicAdd(&hist[d], 1);
                pos_local[i] = lp;
            }
        }
    } else {
        for (int i = lo + t; i < hi; i += 1024) {
            const int v = snd[i];
            const unsigned d = (unsigned)(v - base);
            if (d < (unsigned)RANGE) atomicAdd(&hist[d], 1);
        }
    }
    __syncthreads();
    int* dst = partial + (size_t)((a * NR + r) * NS + s) * RANGE;
    for (int k = t; k < RANGE; k += 1024) dst[k] = hist[k];
}

// ---------------- pass B: scan rcv partials over slices, degrees, rin/rout ----------------
__global__ __launch_bounds__(256) void scanp_kernel(
    int* __restrict__ partial,
    int* __restrict__ dr_i,
    float* __restrict__ rin, float* __restrict__ rout,
    int nN, int NR, int NS)
{
    const int gid = blockIdx.x * 256 + threadIdx.x;
    if (gid >= (NR << RANGE_BITS)) return;
    const int r = gid >> RANGE_BITS;
    const int node = gid & (RANGE - 1);
    int* prcv = partial + (size_t)(r * NS) * RANGE + node;
    int run = 0;
    for (int s = 0; s < NS; ++s) {
        int* p = prcv + (size_t)s * RANGE;
        const int c = *p;
        *p = run;
        run += c;
    }
    const int* psnd = partial + (size_t)((NR + r) * NS) * RANGE + node;
    int tot = 0;
    for (int s = 0; s < NS; ++s) tot += psnd[(size_t)s * RANGE];
    if (gid < nN) {
        dr_i[gid] = run;
        rout[gid] = rsqrtf(fmaxf((float)run, 1.f));
        rin[gid]  = rsqrtf(fmaxf((float)tot, 1.f));
    }
}

// ---------------- scan stage 1 ----------------
__global__ __launch_bounds__(256) void scan1_kernel(const int* __restrict__ cnt,
                                                    int* __restrict__ rowptr,
                                                    int* __restrict__ bsums, int n)
{
    __shared__ int sd[256];
    const int t = threadIdx.x;
    const int base = blockIdx.x * 1024 + t * 4;
    int v0 = (base + 0 < n) ? cnt[base + 0] : 0;
    int v1 = (base + 1 < n) ? cnt[base + 1] : 0;
    int v2 = (base + 2 < n) ? cnt[base + 2] : 0;
    int v3 = (base + 3 < n) ? cnt[base + 3] : 0;
    const int p1 = v0, p2 = v0 + v1, p3 = v0 + v1 + v2;
    const int tot = p3 + v3;
    sd[t] = tot;
    __syncthreads();
    for (int off = 1; off < 256; off <<= 1) {
        int y = (t >= off) ? sd[t - off] : 0;
        __syncthreads();
        sd[t] += y;
        __syncthreads();
    }
    const int excl = sd[t] - tot;
    if (base + 0 < n) rowptr[base + 0] = excl;
    if (base + 1 < n) rowptr[base + 1] = excl + p1;
    if (base + 2 < n) rowptr[base + 2] = excl + p2;
    if (base + 3 < n) rowptr[base + 3] = excl + p3;
    if (t == 255) bsums[blockIdx.x] = sd[255];
}

// ---------------- scan stage 2 ----------------
__global__ __launch_bounds__(256) void scan2_kernel(int* __restrict__ bsums, int nb)
{
    __shared__ int sd[256];
    const int t = threadIdx.x;
    const int v = (t < nb) ? bsums[t] : 0;
    sd[t] = v;
    __syncthreads();
    for (int off = 1; off < 256; off <<= 1) {
        int y = (t >= off) ? sd[t - off] : 0;
        __syncthreads();
        sd[t] += y;
        __syncthreads();
    }
    if (t < nb) bsums[t] = sd[t] - v;
}

// ---------------- scan stage 3 ----------------
__global__ __launch_bounds__(256) void scan3_kernel(int* __restrict__ rowptr,
                                                    const int* __restrict__ bsums,
                                                    int n, int nE)
{
    const int gid = blockIdx.x * 256 + threadIdx.x;
    if (gid < n) rowptr[gid] += bsums[gid >> 10];
    if (gid == 0) rowptr[n] = nE;
}

// ---------------- pass C: atomic-free CSR fill ----------------
__global__ __launch_bounds__(256) void fill_kernel(
    const int* __restrict__ snd, const int* __restrict__ rcv,
    const int* __restrict__ pos_local, const int* __restrict__ partial,
    const int* __restrict__ rowptr, int* __restrict__ csr_src,
    int nE, int NS)
{
    const int i = blockIdx.x * 256 + threadIdx.x;
    if (i >= nE) return;
    const int rv = rcv[i];
    const int r = rv >> RANGE_BITS;
    const int s = i >> SLICE_BITS;
    const int pref = partial[(size_t)(r * NS + s) * RANGE + (rv & (RANGE - 1))];
    const int pos = rowptr[rv] + pref + pos_local[i];
    csr_src[pos] = snd[i];
}

// ---------------- MFMA MLP + W3 projection:
// p = fp16( rin * ( lrelu(lrelu(X@W1+b1)@W2+b2) @ W3 ) )   [N,40]
// 64 rows/block, 4 waves, wave owns 16 rows. A-frags for GEMM1 read directly
// from global X (row-contiguous 8xf32 per lane). Weights staged as W^T fp16 in
// LDS, chunk-XOR swizzled (phys = chunk ^ (row&7)) for uniform bank groups.
// Fragment layout (m89-verified): A/B lane: idx&15 = own-dim row, (idx>>4)*8+j = k;
// C/D: col = lane&15, row = (lane>>4)*4 + reg.
__global__ __launch_bounds__(256) void mlp_kernel(
    const float* __restrict__ X, const float* __restrict__ W1, const float* __restrict__ b1,
    const float* __restrict__ W2, const float* __restrict__ b2, const float* __restrict__ W3,
    const float* __restrict__ rin, __half* __restrict__ p, int nN)
{
    __shared__ uint4 R1[1024];   // W1T[64c][16ch] -> {W2T[64c][8ch] @0, W3T[48c][8ch] @512}
    __shared__ uint4 R2[512];    // h1s[64r][8ch] -> h2s[64r][8ch]   (halves: row stride 64)

    const int t    = threadIdx.x;
    const int w    = t >> 6;         // wave 0..3
    const int l    = t & 63;
    const int lrow = l & 15;         // fragment own-dim index
    const int lq   = l >> 4;         // k-quarter
    const int row0 = blockIdx.x * 64;

    // ---- stage W1T (fp16, [c][k]): wave w covers k in [32w, 32w+32) ----
    {
        const int c = l;
        for (int ch = 0; ch < 4; ++ch) {
            const int kc = 4 * w + ch;                    // 8-k chunk 0..15
            const float* wp = W1 + (kc * 8) * 64 + c;
            uint4 u;
            u.x = pack2h(wp[0],       wp[64]);
            u.y = pack2h(wp[2 * 64],  wp[3 * 64]);
            u.z = pack2h(wp[4 * 64],  wp[5 * 64]);
            u.w = pack2h(wp[6 * 64],  wp[7 * 64]);
            R1[c * 16 + (kc ^ (c & 7))] = u;
        }
    }
    __syncthreads();

    // ---- GEMM1: h1 = lrelu(X@W1+b1); A from global, B from W1T ----
    const int grow = row0 + 16 * w + lrow;
    const bool rowok = grow < nN;
    const float* xr = X + (size_t)grow * 128 + lq * 8;

    f32x4 acc1[4];
#pragma unroll
    for (int nt = 0; nt < 4; ++nt) acc1[nt] = (f32x4){0.f, 0.f, 0.f, 0.f};

#pragma unroll
    for (int ks = 0; ks < 4; ++ks) {
        float4 xa = make_float4(0.f, 0.f, 0.f, 0.f), xb = xa;
        if (rowok) {
            xa = *(const float4*)(xr + 32 * ks);
            xb = *(const float4*)(xr + 32 * ks + 4);
        }
        uint4 au;
        au.x = pack2h(xa.x, xa.y); au.y = pack2h(xa.z, xa.w);
        au.z = pack2h(xb.x, xb.y); au.w = pack2h(xb.z, xb.w);
        const f16x8 af = u4h8(au);
        const int kc = 4 * ks + lq;
#pragma unroll
        for (int nt = 0; nt < 4; ++nt) {
            const int c = 16 * nt + lrow;
            const uint4 bu = R1[c * 16 + (kc ^ (c & 7))];
            acc1[nt] = __builtin_amdgcn_mfma_f32_16x16x32_f16(af, u4h8(bu), acc1[nt], 0, 0, 0);
        }
    }
    __syncthreads();   // W1T reads done

    // ---- h1 -> LDS (R2, swizzled halves); stage W2T + W3T into R1 ----
    {
        __half* hh = (__half*)R2;
#pragma unroll
        for (int nt = 0; nt < 4; ++nt) {
            const int col = 16 * nt + lrow;
            const float bv = b1[col];
            const int ch = col >> 3, cl = col & 7;
#pragma unroll
            for (int r = 0; r < 4; ++r) {
                const int rw = 16 * w + 4 * lq + r;
                hh[rw * 64 + ((ch ^ (rw & 7)) * 8) + cl] = __float2half(lrelu(acc1[nt][r] + bv));
            }
        }
        // W2T: wave w covers k in [16w, 16w+16)
        const int c = l;
#pragma unroll
        for (int ch = 0; ch < 2; ++ch) {
            const int kc = 2 * w + ch;
            const float* wp = W2 + (kc * 8) * 64 + c;
            uint4 u;
            u.x = pack2h(wp[0],      wp[64]);
            u.y = pack2h(wp[2 * 64], wp[3 * 64]);
            u.z = pack2h(wp[4 * 64], wp[5 * 64]);
            u.w = pack2h(wp[6 * 64], wp[7 * 64]);
            R1[c * 8 + (kc ^ (c & 7))] = u;
        }
        if (c < 48) {
            const bool cv = c < 40;
#pragma unroll
            for (int ch = 0; ch < 2; ++ch) {
                const int kc = 2 * w + ch;
                const float* wp = W3 + (kc * 8) * 40 + c;
                uint4 u;
                u.x = pack2h(cv ? wp[0]      : 0.f, cv ? wp[40]     : 0.f);
                u.y = pack2h(cv ? wp[2 * 40] : 0.f, cv ? wp[3 * 40] : 0.f);
                u.z = pack2h(cv ? wp[4 * 40] : 0.f, cv ? wp[5 * 40] : 0.f);
                u.w = pack2h(cv ? wp[6 * 40] : 0.f, cv ? wp[7 * 40] : 0.f);
                R1[512 + c * 8 + (kc ^ (c & 7))] = u;
            }
        }
    }
    __syncthreads();

    // ---- GEMM2: h2 = lrelu(h1@W2+b2) ----
    f32x4 acc2[4];
#pragma unroll
    for (int nt = 0; nt < 4; ++nt) acc2[nt] = (f32x4){0.f, 0.f, 0.f, 0.f};
    {
        const int ar = 16 * w + lrow;
#pragma unroll
        for (int ks = 0; ks < 2; ++ks) {
            const int kc = 4 * ks + lq;
            const f16x8 af = u4h8(R2[ar * 8 + (kc ^ (ar & 7))]);
#pragma unroll
            for (int nt = 0; nt < 4; ++nt) {
                const int c = 16 * nt + lrow;
                const uint4 bu = R1[c * 8 + (kc ^ (c & 7))];
                acc2[nt] = __builtin_amdgcn_mfma_f32_16x16x32_f16(af, u4h8(bu), acc2[nt], 0, 0, 0);
            }
        }
    }
    __syncthreads();   // h1s reads done

    // ---- h2 -> LDS (R2 reused) ----
    {
        __half* hh = (__half*)R2;
#pragma unroll
        for (int nt = 0; nt < 4; ++nt) {
            const int col = 16 * nt + lrow;
            const float bv = b2[col];
            const int ch = col >> 3, cl = col & 7;
#pragma unroll
            for (int r = 0; r < 4; ++r) {
                const int rw = 16 * w + 4 * lq + r;
                hh[rw * 64 + ((ch ^ (rw & 7)) * 8) + cl] = __float2half(lrelu(acc2[nt][r] + bv));
            }
        }
    }
    __syncthreads();

    // ---- GEMM3: p = rin * (h2 @ W3) ----
    f32x4 acc3[3];
#pragma unroll
    for (int nt = 0; nt < 3; ++nt) acc3[nt] = (f32x4){0.f, 0.f, 0.f, 0.f};
    {
        const int ar = 16 * w + lrow;
#pragma unroll
        for (int ks = 0; ks < 2; ++ks) {
            const int kc = 4 * ks + lq;
            const f16x8 af = u4h8(R2[ar * 8 + (kc ^ (ar & 7))]);
#pragma unroll
            for (int nt = 0; nt < 3; ++nt) {
                const int c = 16 * nt + lrow;
                const uint4 bu = R1[512 + c * 8 + (kc ^ (c & 7))];
                acc3[nt] = __builtin_amdgcn_mfma_f32_16x16x32_f16(af, u4h8(bu), acc3[nt], 0, 0, 0);
            }
        }
    }

#pragma unroll
    for (int r = 0; r < 4; ++r) {
        const int gr = row0 + 16 * w + 4 * lq + r;
        if (gr < nN) {
            const float rs = rin[gr];
            __half* pr = p + (size_t)gr * 40;
#pragma unroll
            for (int nt = 0; nt < 3; ++nt) {
                const int col = 16 * nt + lrow;
                if (col < 40) pr[col] = __float2half(acc3[nt][r] * rs);
            }
        }
    }
}

// ---------------- agg1 (fp16 CSR gather): q = rin*rout * sum p[src]; c = rout * sum rin[src]
__global__ __launch_bounds__(256) void agg1_kernel(const __half* __restrict__ p,
                                                   const int* __restrict__ csr_src,
                                                   const int* __restrict__ rowptr,
                                                   const float* __restrict__ rin,
                                                   const float* __restrict__ rout,
                                                   __half* __restrict__ qbuf,
                                                   float* __restrict__ cbuf, int nN)
{
    const int gid = blockIdx.x * 256 + threadIdx.x;
    const int node = gid >> 2;
    const int q4 = gid & 3;
    if (node >= nN) return;
    const int beg = rowptr[node], end = rowptr[node + 1];
    const bool has2 = (q4 == 1);
    float a[16];
#pragma unroll
    for (int j = 0; j < 16; ++j) a[j] = 0.f;
    float cs = 0.f;
    for (int e = beg; e < end; ++e) {
        const int src = csr_src[e];
        const uint4* row = (const uint4*)(p + (size_t)src * 40);
        const uint4 u = row[q4];
        float2 f;
        f = unpack2(u.x); a[0] += f.x; a[1] += f.y;
        f = unpack2(u.y); a[2] += f.x; a[3] += f.y;
        f = unpack2(u.z); a[4] += f.x; a[5] += f.y;
        f = unpack2(u.w); a[6] += f.x; a[7] += f.y;
        if (has2) {
            const uint4 v = row[4];
            f = unpack2(v.x); a[8]  += f.x; a[9]  += f.y;
            f = unpack2(v.y); a[10] += f.x; a[11] += f.y;
            f = unpack2(v.z); a[12] += f.x; a[13] += f.y;
            f = unpack2(v.w); a[14] += f.x; a[15] += f.y;
        }
        if (q4 == 0) cs += rin[src];
    }
    const float sc = rin[node] * rout[node];
    uint4 o;
    o.x = pack2h(a[0] * sc, a[1] * sc);
    o.y = pack2h(a[2] * sc, a[3] * sc);
    o.z = pack2h(a[4] * sc, a[5] * sc);
    o.w = pack2h(a[6] * sc, a[7] * sc);
    uint4* qr = (uint4*)(qbuf + (size_t)node * 40);
    qr[q4] = o;
    if (has2) {
        uint4 o2;
        o2.x = pack2h(a[8]  * sc, a[9]  * sc);
        o2.y = pack2h(a[10] * sc, a[11] * sc);
        o2.z = pack2h(a[12] * sc, a[13] * sc);
        o2.w = pack2h(a[14] * sc, a[15] * sc);
        qr[4] = o2;
    }
    if (q4 == 0) cbuf[node] = cs * rout[node];
}

// ---------------- agg2 + bias-term + softmax -> out (f32) ----------------
__global__ __launch_bounds__(256) void agg2_kernel(const __half* __restrict__ qbuf,
                                                   const int* __restrict__ csr_src,
                                                   const int* __restrict__ rowptr,
                                                   const float* __restrict__ rout,
                                                   const float* __restrict__ cbuf,
                                                   const float* __restrict__ b3,
                                                   float* __restrict__ out, int nN)
{
    const int gid = blockIdx.x * 256 + threadIdx.x;
    const int node = gid >> 2;
    const int q4 = gid & 3;
    if (node >= nN) return;
    const int beg = rowptr[node], end = rowptr[node + 1];
    const bool has2 = (q4 == 1);
    float a[16];
#pragma unroll
    for (int j = 0; j < 16; ++j) a[j] = 0.f;
    for (int e = beg; e < end; ++e) {
        const int src = csr_src[e];
        const uint4* row = (const uint4*)(qbuf + (size_t)src * 40);
        const uint4 u = row[q4];
        float2 f;
        f = unpack2(u.x); a[0] += f.x; a[1] += f.y;
        f = unpack2(u.y); a[2] += f.x; a[3] += f.y;
        f = unpack2(u.z); a[4] += f.x; a[5] += f.y;
        f = unpack2(u.w); a[6] += f.x; a[7] += f.y;
        if (has2) {
            const uint4 v = row[4];
            f = unpack2(v.x); a[8]  += f.x; a[9]  += f.y;
            f = unpack2(v.y); a[10] += f.x; a[11] += f.y;
            f = unpack2(v.z); a[12] += f.x; a[13] += f.y;
            f = unpack2(v.w); a[14] += f.x; a[15] += f.y;
        }
    }
    const float ro = rout[node];
    const float c  = cbuf[node];
    float z[16];
#pragma unroll
    for (int j = 0; j < 8; ++j) z[j] = ro * a[j] + c * b3[q4 * 8 + j];
    if (has2) {
#pragma unroll
        for (int j = 0; j < 8; ++j) z[8 + j] = ro * a[8 + j] + c * b3[32 + j];
    }
    float m = z[0];
#pragma unroll
    for (int j = 1; j < 8; ++j) m = fmaxf(m, z[j]);
    if (has2) {
#pragma unroll
        for (int j = 8; j < 16; ++j) m = fmaxf(m, z[j]);
    }
    m = fmaxf(m, __shfl_xor(m, 1));
    m = fmaxf(m, __shfl_xor(m, 2));
    float s = 0.f;
#pragma unroll
    for (int j = 0; j < 8; ++j) { z[j] = __expf(z[j] - m); s += z[j]; }
    if (has2) {
#pragma unroll
        for (int j = 8; j < 16; ++j) { z[j] = __expf(z[j] - m); s += z[j]; }
    }
    s += __shfl_xor(s, 1);
    s += __shfl_xor(s, 2);
    const float inv = 1.f / s;
    float4* orow = (float4*)(out + (size_t)node * 40);
    orow[q4 * 2 + 0] = make_float4(z[0] * inv, z[1] * inv, z[2] * inv, z[3] * inv);
    orow[q4 * 2 + 1] = make_float4(z[4] * inv, z[5] * inv, z[6] * inv, z[7] * inv);
    if (has2) {
        orow[8] = make_float4(z[8]  * inv, z[9]  * inv, z[10] * inv, z[11] * inv);
        orow[9] = make_float4(z[12] * inv, z[13] * inv, z[14] * inv, z[15] * inv);
    }
}

extern "C" void kernel_launch(void* const* d_in, const int* in_sizes, int n_in,
                              void* d_out, int out_size, void* d_ws, size_t ws_size,
                              hipStream_t stream)
{
    const float* nodes = (const float*)d_in[0];
    const int*   snd   = (const int*)d_in[1];
    const int*   rcv   = (const int*)d_in[2];
    const float* W1    = (const float*)d_in[3];
    const float* b1    = (const float*)d_in[4];
    const float* W2    = (const float*)d_in[5];
    const float* b2    = (const float*)d_in[6];
    const float* W3    = (const float*)d_in[7];
    const float* b3    = (const float*)d_in[8];

    const int nN = in_sizes[0] / 128;
    const int nE = in_sizes[1];
    const int NR = (nN + RANGE - 1) >> RANGE_BITS;   // 7 for N=100000
    const int NS = (nE + SLICE - 1) >> SLICE_BITS;   // 25 for E=1.6M

    size_t off = 0;
    auto alloc = [&](size_t n) { size_t r = off; off += (n + 3) & ~(size_t)3; return r; };
    int*   dr_i    = (int*)d_ws + alloc(nN);
    int*   rowptr  = (int*)d_ws + alloc(nN + 1);
    int*   bsums   = (int*)d_ws + alloc(256);
    float* rin     = (float*)d_ws + alloc(nN);
    float* rout    = (float*)d_ws + alloc(nN);
    float* cbuf    = (float*)d_ws + alloc(nN);
    int*   csr_src = (int*)d_ws + alloc(nE);
    // union region: {partial + pos_local} (dead after fill) overlaps {pbuf + qbuf} (fp16)
    const size_t psz = (size_t)2 * NR * NS * RANGE;
    size_t ubase = alloc(0);
    int*    partial   = (int*)d_ws + ubase;
    int*    pos_local = (int*)d_ws + ubase + psz;
    __half* pbuf      = (__half*)((int*)d_ws + ubase);
    __half* qbuf      = pbuf + (size_t)nN * 40;     // byte offset nN*80, 16B-aligned

    const int nb1 = (nN + 1023) / 1024;

    count_kernel<<<2 * NR * NS, 1024, 0, stream>>>(snd, rcv, partial, pos_local, nE, NR, NS);
    scanp_kernel<<<(NR * RANGE + 255) / 256, 256, 0, stream>>>(partial, dr_i, rin, rout, nN, NR, NS);
    scan1_kernel<<<nb1, 256, 0, stream>>>(dr_i, rowptr, bsums, nN);
    scan2_kernel<<<1, 256, 0, stream>>>(bsums, nb1);
    scan3_kernel<<<(nN + 255) / 256, 256, 0, stream>>>(rowptr, bsums, nN, nE);
    fill_kernel<<<(nE + 255) / 256, 256, 0, stream>>>(snd, rcv, pos_local, partial, rowptr, csr_src, nE, NS);
    mlp_kernel<<<(nN + 63) / 64, 256, 0, stream>>>(nodes, W1, b1, W2, b2, W3, rin, pbuf, nN);
    agg1_kernel<<<((size_t)nN * 4 + 255) / 256, 256, 0, stream>>>(pbuf, csr_src, rowptr, rin, rout, qbuf, cbuf, nN);
    agg2_kernel<<<((size_t)nN * 4 + 255) / 256, 256, 0, stream>>>(qbuf, csr_src, rowptr, rout, cbuf, b3, (float*)d_out, nN);
}

// Round 7
// 194.999 us; speedup vs baseline: 1.2862x; 1.0997x over previous
//
#include <hip/hip_runtime.h>
#include <hip/hip_fp16.h>

#define NEG_SLOPE 0.01f
#define RANGE_BITS 14
#define RANGE (1 << RANGE_BITS)     // 16384 nodes per histogram range (64 KB LDS)
#define SLICE_BITS 16
#define SLICE (1 << SLICE_BITS)     // 65536 edges per slice

typedef _Float16 f16x8 __attribute__((ext_vector_type(8)));
typedef float f32x4 __attribute__((ext_vector_type(4)));

__device__ __forceinline__ float lrelu(float x) { return x > 0.f ? x : NEG_SLOPE * x; }

__device__ __forceinline__ unsigned pack2h(float a, float b) {
    __half2 h = __floats2half2_rn(a, b);
    unsigned u; __builtin_memcpy(&u, &h, 4); return u;
}
__device__ __forceinline__ float2 unpack2(unsigned u) {
    __half2 h = *reinterpret_cast<__half2*>(&u);
    return __half22float2(h);
}
__device__ __forceinline__ f16x8 u4h8(uint4 u) {
    f16x8 r; __builtin_memcpy(&r, &u, 16); return r;
}

// ---------------- pass A: per-(array,range,slice) LDS histogram ----------------
__global__ __launch_bounds__(1024) void count_kernel(
    const int* __restrict__ snd, const int* __restrict__ rcv,
    int* __restrict__ partial, int* __restrict__ pos_local,
    int nE, int NR, int NS)
{
    __shared__ int hist[RANGE];
    const int b = blockIdx.x;
    const int a = b / (NR * NS);
    const int rem = b - a * NR * NS;
    const int r = rem / NS;
    const int s = rem - r * NS;
    const int t = threadIdx.x;
    for (int k = t; k < RANGE; k += 1024) hist[k] = 0;
    __syncthreads();
    const int base = r << RANGE_BITS;
    const int lo = s << SLICE_BITS;
    const int hi = min(lo + SLICE, nE);
    if (a == 0) {
        for (int i = lo + t; i < hi; i += 1024) {
            const int v = rcv[i];
            const unsigned d = (unsigned)(v - base);
            if (d < (unsigned)RANGE) {
                const int lp = atomicAdd(&hist[d], 1);
                pos_local[i] = lp;
            }
        }
    } else {
        for (int i = lo + t; i < hi; i += 1024) {
            const int v = snd[i];
            const unsigned d = (unsigned)(v - base);
            if (d < (unsigned)RANGE) atomicAdd(&hist[d], 1);
        }
    }
    __syncthreads();
    int* dst = partial + (size_t)((a * NR + r) * NS + s) * RANGE;
    for (int k = t; k < RANGE; k += 1024) dst[k] = hist[k];
}

// ---------------- pass B: scan rcv partials over slices, degrees, rin/rout ----------------
__global__ __launch_bounds__(256) void scanp_kernel(
    int* __restrict__ partial,
    int* __restrict__ dr_i,
    float* __restrict__ rin, float* __restrict__ rout,
    int nN, int NR, int NS)
{
    const int gid = blockIdx.x * 256 + threadIdx.x;
    if (gid >= (NR << RANGE_BITS)) return;
    const int r = gid >> RANGE_BITS;
    const int node = gid & (RANGE - 1);
    int* prcv = partial + (size_t)(r * NS) * RANGE + node;
    int run = 0;
    for (int s = 0; s < NS; ++s) {
        int* p = prcv + (size_t)s * RANGE;
        const int c = *p;
        *p = run;
        run += c;
    }
    const int* psnd = partial + (size_t)((NR + r) * NS) * RANGE + node;
    int tot = 0;
    for (int s = 0; s < NS; ++s) tot += psnd[(size_t)s * RANGE];
    if (gid < nN) {
        dr_i[gid] = run;
        rout[gid] = rsqrtf(fmaxf((float)run, 1.f));
        rin[gid]  = rsqrtf(fmaxf((float)tot, 1.f));
    }
}

// ---------------- scan stage 1 ----------------
__global__ __launch_bounds__(256) void scan1_kernel(const int* __restrict__ cnt,
                                                    int* __restrict__ rowptr,
                                                    int* __restrict__ bsums, int n)
{
    __shared__ int sd[256];
    const int t = threadIdx.x;
    const int base = blockIdx.x * 1024 + t * 4;
    int v0 = (base + 0 < n) ? cnt[base + 0] : 0;
    int v1 = (base + 1 < n) ? cnt[base + 1] : 0;
    int v2 = (base + 2 < n) ? cnt[base + 2] : 0;
    int v3 = (base + 3 < n) ? cnt[base + 3] : 0;
    const int p1 = v0, p2 = v0 + v1, p3 = v0 + v1 + v2;
    const int tot = p3 + v3;
    sd[t] = tot;
    __syncthreads();
    for (int off = 1; off < 256; off <<= 1) {
        int y = (t >= off) ? sd[t - off] : 0;
        __syncthreads();
        sd[t] += y;
        __syncthreads();
    }
    const int excl = sd[t] - tot;
    if (base + 0 < n) rowptr[base + 0] = excl;
    if (base + 1 < n) rowptr[base + 1] = excl + p1;
    if (base + 2 < n) rowptr[base + 2] = excl + p2;
    if (base + 3 < n) rowptr[base + 3] = excl + p3;
    if (t == 255) bsums[blockIdx.x] = sd[255];
}

// ---------------- scan stage 2 ----------------
__global__ __launch_bounds__(256) void scan2_kernel(int* __restrict__ bsums, int nb)
{
    __shared__ int sd[256];
    const int t = threadIdx.x;
    const int v = (t < nb) ? bsums[t] : 0;
    sd[t] = v;
    __syncthreads();
    for (int off = 1; off < 256; off <<= 1) {
        int y = (t >= off) ? sd[t - off] : 0;
        __syncthreads();
        sd[t] += y;
        __syncthreads();
    }
    if (t < nb) bsums[t] = sd[t] - v;
}

// ---------------- scan stage 3 ----------------
__global__ __launch_bounds__(256) void scan3_kernel(int* __restrict__ rowptr,
                                                    const int* __restrict__ bsums,
                                                    int n, int nE)
{
    const int gid = blockIdx.x * 256 + threadIdx.x;
    if (gid < n) rowptr[gid] += bsums[gid >> 10];
    if (gid == 0) rowptr[n] = nE;
}

// ---------------- pass C: atomic-free CSR fill ----------------
__global__ __launch_bounds__(256) void fill_kernel(
    const int* __restrict__ snd, const int* __restrict__ rcv,
    const int* __restrict__ pos_local, const int* __restrict__ partial,
    const int* __restrict__ rowptr, int* __restrict__ csr_src,
    int nE, int NS)
{
    const int i = blockIdx.x * 256 + threadIdx.x;
    if (i >= nE) return;
    const int rv = rcv[i];
    const int r = rv >> RANGE_BITS;
    const int s = i >> SLICE_BITS;
    const int pref = partial[(size_t)(r * NS + s) * RANGE + (rv & (RANGE - 1))];
    const int pos = rowptr[rv] + pref + pos_local[i];
    csr_src[pos] = snd[i];
}

// ---------------- MFMA MLP + W3 projection (unchanged from R6) ----------------
__global__ __launch_bounds__(256) void mlp_kernel(
    const float* __restrict__ X, const float* __restrict__ W1, const float* __restrict__ b1,
    const float* __restrict__ W2, const float* __restrict__ b2, const float* __restrict__ W3,
    const float* __restrict__ rin, __half* __restrict__ p, int nN)
{
    __shared__ uint4 R1[1024];   // W1T[64c][16ch] -> {W2T[64c][8ch] @0, W3T[48c][8ch] @512}
    __shared__ uint4 R2[512];    // h1s[64r][8ch] -> h2s[64r][8ch]

    const int t    = threadIdx.x;
    const int w    = t >> 6;
    const int l    = t & 63;
    const int lrow = l & 15;
    const int lq   = l >> 4;
    const int row0 = blockIdx.x * 64;

    {
        const int c = l;
        for (int ch = 0; ch < 4; ++ch) {
            const int kc = 4 * w + ch;
            const float* wp = W1 + (kc * 8) * 64 + c;
            uint4 u;
            u.x = pack2h(wp[0],       wp[64]);
            u.y = pack2h(wp[2 * 64],  wp[3 * 64]);
            u.z = pack2h(wp[4 * 64],  wp[5 * 64]);
            u.w = pack2h(wp[6 * 64],  wp[7 * 64]);
            R1[c * 16 + (kc ^ (c & 7))] = u;
        }
    }
    __syncthreads();

    const int grow = row0 + 16 * w + lrow;
    const bool rowok = grow < nN;
    const float* xr = X + (size_t)grow * 128 + lq * 8;

    f32x4 acc1[4];
#pragma unroll
    for (int nt = 0; nt < 4; ++nt) acc1[nt] = (f32x4){0.f, 0.f, 0.f, 0.f};

#pragma unroll
    for (int ks = 0; ks < 4; ++ks) {
        float4 xa = make_float4(0.f, 0.f, 0.f, 0.f), xb = xa;
        if (rowok) {
            xa = *(const float4*)(xr + 32 * ks);
            xb = *(const float4*)(xr + 32 * ks + 4);
        }
        uint4 au;
        au.x = pack2h(xa.x, xa.y); au.y = pack2h(xa.z, xa.w);
        au.z = pack2h(xb.x, xb.y); au.w = pack2h(xb.z, xb.w);
        const f16x8 af = u4h8(au);
        const int kc = 4 * ks + lq;
#pragma unroll
        for (int nt = 0; nt < 4; ++nt) {
            const int c = 16 * nt + lrow;
            const uint4 bu = R1[c * 16 + (kc ^ (c & 7))];
            acc1[nt] = __builtin_amdgcn_mfma_f32_16x16x32_f16(af, u4h8(bu), acc1[nt], 0, 0, 0);
        }
    }
    __syncthreads();

    {
        __half* hh = (__half*)R2;
#pragma unroll
        for (int nt = 0; nt < 4; ++nt) {
            const int col = 16 * nt + lrow;
            const float bv = b1[col];
            const int ch = col >> 3, cl = col & 7;
#pragma unroll
            for (int r = 0; r < 4; ++r) {
                const int rw = 16 * w + 4 * lq + r;
                hh[rw * 64 + ((ch ^ (rw & 7)) * 8) + cl] = __float2half(lrelu(acc1[nt][r] + bv));
            }
        }
        const int c = l;
#pragma unroll
        for (int ch = 0; ch < 2; ++ch) {
            const int kc = 2 * w + ch;
            const float* wp = W2 + (kc * 8) * 64 + c;
            uint4 u;
            u.x = pack2h(wp[0],      wp[64]);
            u.y = pack2h(wp[2 * 64], wp[3 * 64]);
            u.z = pack2h(wp[4 * 64], wp[5 * 64]);
            u.w = pack2h(wp[6 * 64], wp[7 * 64]);
            R1[c * 8 + (kc ^ (c & 7))] = u;
        }
        if (c < 48) {
            const bool cv = c < 40;
#pragma unroll
            for (int ch = 0; ch < 2; ++ch) {
                const int kc = 2 * w + ch;
                const float* wp = W3 + (kc * 8) * 40 + c;
                uint4 u;
                u.x = pack2h(cv ? wp[0]      : 0.f, cv ? wp[40]     : 0.f);
                u.y = pack2h(cv ? wp[2 * 40] : 0.f, cv ? wp[3 * 40] : 0.f);
                u.z = pack2h(cv ? wp[4 * 40] : 0.f, cv ? wp[5 * 40] : 0.f);
                u.w = pack2h(cv ? wp[6 * 40] : 0.f, cv ? wp[7 * 40] : 0.f);
                R1[512 + c * 8 + (kc ^ (c & 7))] = u;
            }
        }
    }
    __syncthreads();

    f32x4 acc2[4];
#pragma unroll
    for (int nt = 0; nt < 4; ++nt) acc2[nt] = (f32x4){0.f, 0.f, 0.f, 0.f};
    {
        const int ar = 16 * w + lrow;
#pragma unroll
        for (int ks = 0; ks < 2; ++ks) {
            const int kc = 4 * ks + lq;
            const f16x8 af = u4h8(R2[ar * 8 + (kc ^ (ar & 7))]);
#pragma unroll
            for (int nt = 0; nt < 4; ++nt) {
                const int c = 16 * nt + lrow;
                const uint4 bu = R1[c * 8 + (kc ^ (c & 7))];
                acc2[nt] = __builtin_amdgcn_mfma_f32_16x16x32_f16(af, u4h8(bu), acc2[nt], 0, 0, 0);
            }
        }
    }
    __syncthreads();

    {
        __half* hh = (__half*)R2;
#pragma unroll
        for (int nt = 0; nt < 4; ++nt) {
            const int col = 16 * nt + lrow;
            const float bv = b2[col];
            const int ch = col >> 3, cl = col & 7;
#pragma unroll
            for (int r = 0; r < 4; ++r) {
                const int rw = 16 * w + 4 * lq + r;
                hh[rw * 64 + ((ch ^ (rw & 7)) * 8) + cl] = __float2half(lrelu(acc2[nt][r] + bv));
            }
        }
    }
    __syncthreads();

    f32x4 acc3[3];
#pragma unroll
    for (int nt = 0; nt < 3; ++nt) acc3[nt] = (f32x4){0.f, 0.f, 0.f, 0.f};
    {
        const int ar = 16 * w + lrow;
#pragma unroll
        for (int ks = 0; ks < 2; ++ks) {
            const int kc = 4 * ks + lq;
            const f16x8 af = u4h8(R2[ar * 8 + (kc ^ (ar & 7))]);
#pragma unroll
            for (int nt = 0; nt < 3; ++nt) {
                const int c = 16 * nt + lrow;
                const uint4 bu = R1[512 + c * 8 + (kc ^ (c & 7))];
                acc3[nt] = __builtin_amdgcn_mfma_f32_16x16x32_f16(af, u4h8(bu), acc3[nt], 0, 0, 0);
            }
        }
    }

#pragma unroll
    for (int r = 0; r < 4; ++r) {
        const int gr = row0 + 16 * w + 4 * lq + r;
        if (gr < nN) {
            const float rs = rin[gr];
            __half* pr = p + (size_t)gr * 40;
#pragma unroll
            for (int nt = 0; nt < 3; ++nt) {
                const int col = 16 * nt + lrow;
                if (col < 40) pr[col] = __float2half(acc3[nt][r] * rs);
            }
        }
    }
}

// ---------------- agg1: 8 lanes/node, 8-edge pipelined gather ----------------
// lane j<5: 16B chunk j of p-row; lane 5: rin side-sum; lanes 6,7 idle.
__global__ __launch_bounds__(256) void agg1_kernel(const __half* __restrict__ p,
                                                   const int* __restrict__ csr_src,
                                                   const int* __restrict__ rowptr,
                                                   const float* __restrict__ rin,
                                                   const float* __restrict__ rout,
                                                   __half* __restrict__ qbuf,
                                                   float* __restrict__ cbuf, int nN)
{
    const int gid = blockIdx.x * 256 + threadIdx.x;
    const int node = gid >> 3;
    const int j = gid & 7;
    if (node >= nN) return;
    const int beg = rowptr[node], end = rowptr[node + 1];
    const bool isch = (j < 5);
    const bool isr  = (j == 5);
    float a[8];
#pragma unroll
    for (int k = 0; k < 8; ++k) a[k] = 0.f;
    float cs = 0.f;

    int e = beg;
    for (; e + 8 <= end; e += 8) {
        int s[8];
#pragma unroll
        for (int b = 0; b < 8; ++b) s[b] = csr_src[e + b];
        if (isch) {
            uint4 u[8];
#pragma unroll
            for (int b = 0; b < 8; ++b)
                u[b] = ((const uint4*)(p + (size_t)s[b] * 40))[j];
#pragma unroll
            for (int b = 0; b < 8; ++b) {
                float2 f;
                f = unpack2(u[b].x); a[0] += f.x; a[1] += f.y;
                f = unpack2(u[b].y); a[2] += f.x; a[3] += f.y;
                f = unpack2(u[b].z); a[4] += f.x; a[5] += f.y;
                f = unpack2(u[b].w); a[6] += f.x; a[7] += f.y;
            }
        } else if (isr) {
            float rr[8];
#pragma unroll
            for (int b = 0; b < 8; ++b) rr[b] = rin[s[b]];
#pragma unroll
            for (int b = 0; b < 8; ++b) cs += rr[b];
        }
    }
    for (; e < end; ++e) {
        const int src = csr_src[e];
        if (isch) {
            const uint4 u = ((const uint4*)(p + (size_t)src * 40))[j];
            float2 f;
            f = unpack2(u.x); a[0] += f.x; a[1] += f.y;
            f = unpack2(u.y); a[2] += f.x; a[3] += f.y;
            f = unpack2(u.z); a[4] += f.x; a[5] += f.y;
            f = unpack2(u.w); a[6] += f.x; a[7] += f.y;
        } else if (isr) {
            cs += rin[src];
        }
    }

    if (isch) {
        const float sc = rin[node] * rout[node];
        uint4 o;
        o.x = pack2h(a[0] * sc, a[1] * sc);
        o.y = pack2h(a[2] * sc, a[3] * sc);
        o.z = pack2h(a[4] * sc, a[5] * sc);
        o.w = pack2h(a[6] * sc, a[7] * sc);
        ((uint4*)(qbuf + (size_t)node * 40))[j] = o;
    } else if (isr) {
        cbuf[node] = cs * rout[node];
    }
}

// ---------------- agg2 + bias-term + softmax -> out (f32); 8 lanes/node ----------------
__global__ __launch_bounds__(256) void agg2_kernel(const __half* __restrict__ qbuf,
                                                   const int* __restrict__ csr_src,
                                                   const int* __restrict__ rowptr,
                                                   const float* __restrict__ rout,
                                                   const float* __restrict__ cbuf,
                                                   const float* __restrict__ b3,
                                                   float* __restrict__ out, int nN)
{
    const int gid = blockIdx.x * 256 + threadIdx.x;
    const int node = gid >> 3;
    const int j = gid & 7;
    if (node >= nN) return;
    const int beg = rowptr[node], end = rowptr[node + 1];
    const bool isch = (j < 5);
    float a[8];
#pragma unroll
    for (int k = 0; k < 8; ++k) a[k] = 0.f;

    int e = beg;
    for (; e + 8 <= end; e += 8) {
        int s[8];
#pragma unroll
        for (int b = 0; b < 8; ++b) s[b] = csr_src[e + b];
        if (isch) {
            uint4 u[8];
#pragma unroll
            for (int b = 0; b < 8; ++b)
                u[b] = ((const uint4*)(qbuf + (size_t)s[b] * 40))[j];
#pragma unroll
            for (int b = 0; b < 8; ++b) {
                float2 f;
                f = unpack2(u[b].x); a[0] += f.x; a[1] += f.y;
                f = unpack2(u[b].y); a[2] += f.x; a[3] += f.y;
                f = unpack2(u[b].z); a[4] += f.x; a[5] += f.y;
                f = unpack2(u[b].w); a[6] += f.x; a[7] += f.y;
            }
        }
    }
    for (; e < end; ++e) {
        const int src = csr_src[e];
        if (isch) {
            const uint4 u = ((const uint4*)(qbuf + (size_t)src * 40))[j];
            float2 f;
            f = unpack2(u.x); a[0] += f.x; a[1] += f.y;
            f = unpack2(u.y); a[2] += f.x; a[3] += f.y;
            f = unpack2(u.z); a[4] += f.x; a[5] += f.y;
            f = unpack2(u.w); a[6] += f.x; a[7] += f.y;
        }
    }

    const float ro = rout[node];
    const float c  = cbuf[node];
    float z[8];
    float m = -1e30f, ssum = 0.f;
    if (isch) {
#pragma unroll
        for (int k = 0; k < 8; ++k) {
            z[k] = ro * a[k] + c * b3[j * 8 + k];
            m = fmaxf(m, z[k]);
        }
    }
    m = fmaxf(m, __shfl_xor(m, 1));
    m = fmaxf(m, __shfl_xor(m, 2));
    m = fmaxf(m, __shfl_xor(m, 4));
    if (isch) {
#pragma unroll
        for (int k = 0; k < 8; ++k) { z[k] = __expf(z[k] - m); ssum += z[k]; }
    }
    ssum += __shfl_xor(ssum, 1);
    ssum += __shfl_xor(ssum, 2);
    ssum += __shfl_xor(ssum, 4);
    if (isch) {
        const float inv = 1.f / ssum;
        float4* orow = (float4*)(out + (size_t)node * 40);
        orow[j * 2 + 0] = make_float4(z[0] * inv, z[1] * inv, z[2] * inv, z[3] * inv);
        orow[j * 2 + 1] = make_float4(z[4] * inv, z[5] * inv, z[6] * inv, z[7] * inv);
    }
}

extern "C" void kernel_launch(void* const* d_in, const int* in_sizes, int n_in,
                              void* d_out, int out_size, void* d_ws, size_t ws_size,
                              hipStream_t stream)
{
    const float* nodes = (const float*)d_in[0];
    const int*   snd   = (const int*)d_in[1];
    const int*   rcv   = (const int*)d_in[2];
    const float* W1    = (const float*)d_in[3];
    const float* b1    = (const float*)d_in[4];
    const float* W2    = (const float*)d_in[5];
    const float* b2    = (const float*)d_in[6];
    const float* W3    = (const float*)d_in[7];
    const float* b3    = (const float*)d_in[8];

    const int nN = in_sizes[0] / 128;
    const int nE = in_sizes[1];
    const int NR = (nN + RANGE - 1) >> RANGE_BITS;   // 7 for N=100000
    const int NS = (nE + SLICE - 1) >> SLICE_BITS;   // 25 for E=1.6M

    size_t off = 0;
    auto alloc = [&](size_t n) { size_t r = off; off += (n + 3) & ~(size_t)3; return r; };
    int*   dr_i    = (int*)d_ws + alloc(nN);
    int*   rowptr  = (int*)d_ws + alloc(nN + 1);
    int*   bsums   = (int*)d_ws + alloc(256);
    float* rin     = (float*)d_ws + alloc(nN);
    float* rout    = (float*)d_ws + alloc(nN);
    float* cbuf    = (float*)d_ws + alloc(nN);
    int*   csr_src = (int*)d_ws + alloc(nE);
    // union region: {partial + pos_local} (dead after fill) overlaps {pbuf + qbuf} (fp16)
    const size_t psz = (size_t)2 * NR * NS * RANGE;
    size_t ubase = alloc(0);
    int*    partial   = (int*)d_ws + ubase;
    int*    pos_local = (int*)d_ws + ubase + psz;
    __half* pbuf      = (__half*)((int*)d_ws + ubase);
    __half* qbuf      = pbuf + (size_t)nN * 40;     // byte offset nN*80, 16B-aligned

    const int nb1 = (nN + 1023) / 1024;

    count_kernel<<<2 * NR * NS, 1024, 0, stream>>>(snd, rcv, partial, pos_local, nE, NR, NS);
    scanp_kernel<<<(NR * RANGE + 255) / 256, 256, 0, stream>>>(partial, dr_i, rin, rout, nN, NR, NS);
    scan1_kernel<<<nb1, 256, 0, stream>>>(dr_i, rowptr, bsums, nN);
    scan2_kernel<<<1, 256, 0, stream>>>(bsums, nb1);
    scan3_kernel<<<(nN + 255) / 256, 256, 0, stream>>>(rowptr, bsums, nN, nE);
    fill_kernel<<<(nE + 255) / 256, 256, 0, stream>>>(snd, rcv, pos_local, partial, rowptr, csr_src, nE, NS);
    mlp_kernel<<<(nN + 63) / 64, 256, 0, stream>>>(nodes, W1, b1, W2, b2, W3, rin, pbuf, nN);
    agg1_kernel<<<((size_t)nN * 8 + 255) / 256, 256, 0, stream>>>(pbuf, csr_src, rowptr, rin, rout, qbuf, cbuf, nN);
    agg2_kernel<<<((size_t)nN * 8 + 255) / 256, 256, 0, stream>>>(qbuf, csr_src, rowptr, rout, cbuf, b3, (float*)d_out, nN);
}

// Round 8
// 174.208 us; speedup vs baseline: 1.4397x; 1.1193x over previous
//
#include <hip/hip_runtime.h>
#include <hip/hip_fp16.h>

#define NEG_SLOPE 0.01f
#define RANGE_BITS 15
#define RANGE (1 << RANGE_BITS)     // 32768 nodes per histogram range (16-bit counters, 64 KB LDS)
#define HWORDS (RANGE / 2)          // 16384 packed uint32 words
#define SLICE_BITS 16
#define SLICE (1 << SLICE_BITS)     // 65536 edges per slice

typedef _Float16 f16x8 __attribute__((ext_vector_type(8)));
typedef float f32x4 __attribute__((ext_vector_type(4)));

__device__ __forceinline__ float lrelu(float x) { return x > 0.f ? x : NEG_SLOPE * x; }

__device__ __forceinline__ unsigned pack2h(float a, float b) {
    __half2 h = __floats2half2_rn(a, b);
    unsigned u; __builtin_memcpy(&u, &h, 4); return u;
}
__device__ __forceinline__ float2 unpack2(unsigned u) {
    __half2 h = *reinterpret_cast<__half2*>(&u);
    return __half22float2(h);
}
__device__ __forceinline__ f16x8 u4h8(uint4 u) {
    f16x8 r; __builtin_memcpy(&r, &u, 16); return r;
}

// ---------------- pass A: per-(array,range,slice) LDS histogram, 16-bit counters ----------------
__global__ __launch_bounds__(1024) void count_kernel(
    const int* __restrict__ snd, const int* __restrict__ rcv,
    unsigned* __restrict__ partial, unsigned short* __restrict__ pos16,
    int nE, int NR, int NS)
{
    __shared__ unsigned hist[HWORDS];    // 2 nodes per word
    const int b = blockIdx.x;
    const int a = b / (NR * NS);
    const int rem = b - a * NR * NS;
    const int r = rem / NS;
    const int s = rem - r * NS;
    const int t = threadIdx.x;
    for (int k = t; k < HWORDS; k += 1024) hist[k] = 0u;
    __syncthreads();
    const int base = r << RANGE_BITS;
    const int lo = s << SLICE_BITS;
    const int hi = min(lo + SLICE, nE);
    if (a == 0) {
        for (int i = lo + t; i < hi; i += 1024) {
            const int v = rcv[i];
            const unsigned d = (unsigned)(v - base);
            if (d < (unsigned)RANGE) {
                const unsigned sh = (d & 1u) << 4;
                const unsigned old = atomicAdd(&hist[d >> 1], 1u << sh);
                pos16[i] = (unsigned short)((old >> sh) & 0xffffu);
            }
        }
    } else {
        for (int i = lo + t; i < hi; i += 1024) {
            const int v = snd[i];
            const unsigned d = (unsigned)(v - base);
            if (d < (unsigned)RANGE) atomicAdd(&hist[d >> 1], 1u << ((d & 1u) << 4));
        }
    }
    __syncthreads();
    unsigned* dst = partial + (size_t)((a * NR + r) * NS + s) * HWORDS;
    for (int k = t; k < HWORDS; k += 1024) dst[k] = hist[k];
}

// ---------------- pass B: scan rcv partials over slices (word = 2 nodes per thread) ----------------
__global__ __launch_bounds__(256) void scanp_kernel(
    unsigned* __restrict__ partial,
    int* __restrict__ dr_i,
    float* __restrict__ rin, float* __restrict__ rout,
    int nN, int NR, int NS)
{
    const int gid = blockIdx.x * 256 + threadIdx.x;
    if (gid >= NR * HWORDS) return;
    const int r  = gid >> (RANGE_BITS - 1);
    const int wd = gid & (HWORDS - 1);
    unsigned* prcv = partial + (size_t)(r * NS) * HWORDS + wd;
    unsigned run0 = 0, run1 = 0;
    for (int s = 0; s < NS; ++s) {
        unsigned* p = prcv + (size_t)s * HWORDS;
        const unsigned c = *p;
        *p = run0 | (run1 << 16);
        run0 += c & 0xffffu;
        run1 += c >> 16;
    }
    const unsigned* psnd = partial + (size_t)((NR + r) * NS) * HWORDS + wd;
    unsigned t0 = 0, t1 = 0;
    for (int s = 0; s < NS; ++s) {
        const unsigned c = psnd[(size_t)s * HWORDS];
        t0 += c & 0xffffu;
        t1 += c >> 16;
    }
    const int n0 = (r << RANGE_BITS) + 2 * wd;
    if (n0 < nN) {
        dr_i[n0] = (int)run0;
        rout[n0] = rsqrtf(fmaxf((float)run0, 1.f));
        rin[n0]  = rsqrtf(fmaxf((float)t0, 1.f));
    }
    if (n0 + 1 < nN) {
        dr_i[n0 + 1] = (int)run1;
        rout[n0 + 1] = rsqrtf(fmaxf((float)run1, 1.f));
        rin[n0 + 1]  = rsqrtf(fmaxf((float)t1, 1.f));
    }
}

// ---------------- scan stage 1 ----------------
__global__ __launch_bounds__(256) void scan1_kernel(const int* __restrict__ cnt,
                                                    int* __restrict__ rowptr,
                                                    int* __restrict__ bsums, int n)
{
    __shared__ int sd[256];
    const int t = threadIdx.x;
    const int base = blockIdx.x * 1024 + t * 4;
    int v0 = (base + 0 < n) ? cnt[base + 0] : 0;
    int v1 = (base + 1 < n) ? cnt[base + 1] : 0;
    int v2 = (base + 2 < n) ? cnt[base + 2] : 0;
    int v3 = (base + 3 < n) ? cnt[base + 3] : 0;
    const int p1 = v0, p2 = v0 + v1, p3 = v0 + v1 + v2;
    const int tot = p3 + v3;
    sd[t] = tot;
    __syncthreads();
    for (int off = 1; off < 256; off <<= 1) {
        int y = (t >= off) ? sd[t - off] : 0;
        __syncthreads();
        sd[t] += y;
        __syncthreads();
    }
    const int excl = sd[t] - tot;
    if (base + 0 < n) rowptr[base + 0] = excl;
    if (base + 1 < n) rowptr[base + 1] = excl + p1;
    if (base + 2 < n) rowptr[base + 2] = excl + p2;
    if (base + 3 < n) rowptr[base + 3] = excl + p3;
    if (t == 255) bsums[blockIdx.x] = sd[255];
}

// ---------------- scan stage 2 ----------------
__global__ __launch_bounds__(256) void scan2_kernel(int* __restrict__ bsums, int nb)
{
    __shared__ int sd[256];
    const int t = threadIdx.x;
    const int v = (t < nb) ? bsums[t] : 0;
    sd[t] = v;
    __syncthreads();
    for (int off = 1; off < 256; off <<= 1) {
        int y = (t >= off) ? sd[t - off] : 0;
        __syncthreads();
        sd[t] += y;
        __syncthreads();
    }
    if (t < nb) bsums[t] = sd[t] - v;
}

// ---------------- scan stage 3 ----------------
__global__ __launch_bounds__(256) void scan3_kernel(int* __restrict__ rowptr,
                                                    const int* __restrict__ bsums,
                                                    int n, int nE)
{
    const int gid = blockIdx.x * 256 + threadIdx.x;
    if (gid < n) rowptr[gid] += bsums[gid >> 10];
    if (gid == 0) rowptr[n] = nE;
}

// ---------------- pass C: atomic-free CSR fill ----------------
__global__ __launch_bounds__(256) void fill_kernel(
    const int* __restrict__ snd, const int* __restrict__ rcv,
    const unsigned short* __restrict__ pos16, const unsigned* __restrict__ partial,
    const int* __restrict__ rowptr, int* __restrict__ csr_src,
    int nE, int NS)
{
    const int i = blockIdx.x * 256 + threadIdx.x;
    if (i >= nE) return;
    const int rv = rcv[i];
    const int r = rv >> RANGE_BITS;
    const int s = i >> SLICE_BITS;
    const unsigned pw = partial[(size_t)(r * NS + s) * HWORDS + ((rv & (RANGE - 1)) >> 1)];
    const int pref = (int)((pw >> ((rv & 1) << 4)) & 0xffffu);
    const int pos = rowptr[rv] + pref + (int)pos16[i];
    csr_src[pos] = snd[i];
}

// ---------------- MFMA MLP + W3 projection (unchanged from R6) ----------------
__global__ __launch_bounds__(256) void mlp_kernel(
    const float* __restrict__ X, const float* __restrict__ W1, const float* __restrict__ b1,
    const float* __restrict__ W2, const float* __restrict__ b2, const float* __restrict__ W3,
    const float* __restrict__ rin, __half* __restrict__ p, int nN)
{
    __shared__ uint4 R1[1024];
    __shared__ uint4 R2[512];

    const int t    = threadIdx.x;
    const int w    = t >> 6;
    const int l    = t & 63;
    const int lrow = l & 15;
    const int lq   = l >> 4;
    const int row0 = blockIdx.x * 64;

    {
        const int c = l;
        for (int ch = 0; ch < 4; ++ch) {
            const int kc = 4 * w + ch;
            const float* wp = W1 + (kc * 8) * 64 + c;
            uint4 u;
            u.x = pack2h(wp[0],       wp[64]);
            u.y = pack2h(wp[2 * 64],  wp[3 * 64]);
            u.z = pack2h(wp[4 * 64],  wp[5 * 64]);
            u.w = pack2h(wp[6 * 64],  wp[7 * 64]);
            R1[c * 16 + (kc ^ (c & 7))] = u;
        }
    }
    __syncthreads();

    const int grow = row0 + 16 * w + lrow;
    const bool rowok = grow < nN;
    const float* xr = X + (size_t)grow * 128 + lq * 8;

    f32x4 acc1[4];
#pragma unroll
    for (int nt = 0; nt < 4; ++nt) acc1[nt] = (f32x4){0.f, 0.f, 0.f, 0.f};

#pragma unroll
    for (int ks = 0; ks < 4; ++ks) {
        float4 xa = make_float4(0.f, 0.f, 0.f, 0.f), xb = xa;
        if (rowok) {
            xa = *(const float4*)(xr + 32 * ks);
            xb = *(const float4*)(xr + 32 * ks + 4);
        }
        uint4 au;
        au.x = pack2h(xa.x, xa.y); au.y = pack2h(xa.z, xa.w);
        au.z = pack2h(xb.x, xb.y); au.w = pack2h(xb.z, xb.w);
        const f16x8 af = u4h8(au);
        const int kc = 4 * ks + lq;
#pragma unroll
        for (int nt = 0; nt < 4; ++nt) {
            const int c = 16 * nt + lrow;
            const uint4 bu = R1[c * 16 + (kc ^ (c & 7))];
            acc1[nt] = __builtin_amdgcn_mfma_f32_16x16x32_f16(af, u4h8(bu), acc1[nt], 0, 0, 0);
        }
    }
    __syncthreads();

    {
        __half* hh = (__half*)R2;
#pragma unroll
        for (int nt = 0; nt < 4; ++nt) {
            const int col = 16 * nt + lrow;
            const float bv = b1[col];
            const int ch = col >> 3, cl = col & 7;
#pragma unroll
            for (int r = 0; r < 4; ++r) {
                const int rw = 16 * w + 4 * lq + r;
                hh[rw * 64 + ((ch ^ (rw & 7)) * 8) + cl] = __float2half(lrelu(acc1[nt][r] + bv));
            }
        }
        const int c = l;
#pragma unroll
        for (int ch = 0; ch < 2; ++ch) {
            const int kc = 2 * w + ch;
            const float* wp = W2 + (kc * 8) * 64 + c;
            uint4 u;
            u.x = pack2h(wp[0],      wp[64]);
            u.y = pack2h(wp[2 * 64], wp[3 * 64]);
            u.z = pack2h(wp[4 * 64], wp[5 * 64]);
            u.w = pack2h(wp[6 * 64], wp[7 * 64]);
            R1[c * 8 + (kc ^ (c & 7))] = u;
        }
        if (c < 48) {
            const bool cv = c < 40;
#pragma unroll
            for (int ch = 0; ch < 2; ++ch) {
                const int kc = 2 * w + ch;
                const float* wp = W3 + (kc * 8) * 40 + c;
                uint4 u;
                u.x = pack2h(cv ? wp[0]      : 0.f, cv ? wp[40]     : 0.f);
                u.y = pack2h(cv ? wp[2 * 40] : 0.f, cv ? wp[3 * 40] : 0.f);
                u.z = pack2h(cv ? wp[4 * 40] : 0.f, cv ? wp[5 * 40] : 0.f);
                u.w = pack2h(cv ? wp[6 * 40] : 0.f, cv ? wp[7 * 40] : 0.f);
                R1[512 + c * 8 + (kc ^ (c & 7))] = u;
            }
        }
    }
    __syncthreads();

    f32x4 acc2[4];
#pragma unroll
    for (int nt = 0; nt < 4; ++nt) acc2[nt] = (f32x4){0.f, 0.f, 0.f, 0.f};
    {
        const int ar = 16 * w + lrow;
#pragma unroll
        for (int ks = 0; ks < 2; ++ks) {
            const int kc = 4 * ks + lq;
            const f16x8 af = u4h8(R2[ar * 8 + (kc ^ (ar & 7))]);
#pragma unroll
            for (int nt = 0; nt < 4; ++nt) {
                const int c = 16 * nt + lrow;
                const uint4 bu = R1[c * 8 + (kc ^ (c & 7))];
                acc2[nt] = __builtin_amdgcn_mfma_f32_16x16x32_f16(af, u4h8(bu), acc2[nt], 0, 0, 0);
            }
        }
    }
    __syncthreads();

    {
        __half* hh = (__half*)R2;
#pragma unroll
        for (int nt = 0; nt < 4; ++nt) {
            const int col = 16 * nt + lrow;
            const float bv = b2[col];
            const int ch = col >> 3, cl = col & 7;
#pragma unroll
            for (int r = 0; r < 4; ++r) {
                const int rw = 16 * w + 4 * lq + r;
                hh[rw * 64 + ((ch ^ (rw & 7)) * 8) + cl] = __float2half(lrelu(acc2[nt][r] + bv));
            }
        }
    }
    __syncthreads();

    f32x4 acc3[3];
#pragma unroll
    for (int nt = 0; nt < 3; ++nt) acc3[nt] = (f32x4){0.f, 0.f, 0.f, 0.f};
    {
        const int ar = 16 * w + lrow;
#pragma unroll
        for (int ks = 0; ks < 2; ++ks) {
            const int kc = 4 * ks + lq;
            const f16x8 af = u4h8(R2[ar * 8 + (kc ^ (ar & 7))]);
#pragma unroll
            for (int nt = 0; nt < 3; ++nt) {
                const int c = 16 * nt + lrow;
                const uint4 bu = R1[512 + c * 8 + (kc ^ (c & 7))];
                acc3[nt] = __builtin_amdgcn_mfma_f32_16x16x32_f16(af, u4h8(bu), acc3[nt], 0, 0, 0);
            }
        }
    }

#pragma unroll
    for (int r = 0; r < 4; ++r) {
        const int gr = row0 + 16 * w + 4 * lq + r;
        if (gr < nN) {
            const float rs = rin[gr];
            __half* pr = p + (size_t)gr * 40;
#pragma unroll
            for (int nt = 0; nt < 3; ++nt) {
                const int col = 16 * nt + lrow;
                if (col < 40) pr[col] = __float2half(acc3[nt][r] * rs);
            }
        }
    }
}

// ---------------- agg1: 8 lanes/node, fully-pipelined masked batches ----------------
__global__ __launch_bounds__(256) void agg1_kernel(const __half* __restrict__ p,
                                                   const int* __restrict__ csr_src,
                                                   const int* __restrict__ rowptr,
                                                   const float* __restrict__ rin,
                                                   const float* __restrict__ rout,
                                                   __half* __restrict__ qbuf,
                                                   float* __restrict__ cbuf, int nN)
{
    const int gid = blockIdx.x * 256 + threadIdx.x;
    const int node = gid >> 3;
    const int j = gid & 7;
    if (node >= nN) return;
    const int beg = rowptr[node], end = rowptr[node + 1];
    const bool isch = (j < 5);
    const bool isr  = (j == 5);
    float a[8];
#pragma unroll
    for (int k = 0; k < 8; ++k) a[k] = 0.f;
    float cs = 0.f;

    for (int e = beg; e < end; e += 8) {
        int s[8];
#pragma unroll
        for (int b = 0; b < 8; ++b) {
            const int idx = e + b;
            s[b] = csr_src[idx < end ? idx : end - 1];
        }
        if (isch) {
            uint4 u[8];
#pragma unroll
            for (int b = 0; b < 8; ++b)
                u[b] = ((const uint4*)(p + (size_t)s[b] * 40))[j];
#pragma unroll
            for (int b = 0; b < 8; ++b) {
                if (e + b < end) {
                    float2 f;
                    f = unpack2(u[b].x); a[0] += f.x; a[1] += f.y;
                    f = unpack2(u[b].y); a[2] += f.x; a[3] += f.y;
                    f = unpack2(u[b].z); a[4] += f.x; a[5] += f.y;
                    f = unpack2(u[b].w); a[6] += f.x; a[7] += f.y;
                }
            }
        } else if (isr) {
            float rr[8];
#pragma unroll
            for (int b = 0; b < 8; ++b) rr[b] = rin[s[b]];
#pragma unroll
            for (int b = 0; b < 8; ++b)
                if (e + b < end) cs += rr[b];
        }
    }

    if (isch) {
        const float sc = rin[node] * rout[node];
        uint4 o;
        o.x = pack2h(a[0] * sc, a[1] * sc);
        o.y = pack2h(a[2] * sc, a[3] * sc);
        o.z = pack2h(a[4] * sc, a[5] * sc);
        o.w = pack2h(a[6] * sc, a[7] * sc);
        ((uint4*)(qbuf + (size_t)node * 40))[j] = o;
    } else if (isr) {
        cbuf[node] = cs * rout[node];
    }
}

// ---------------- agg2 + bias-term + softmax -> out (f32); 8 lanes/node ----------------
__global__ __launch_bounds__(256) void agg2_kernel(const __half* __restrict__ qbuf,
                                                   const int* __restrict__ csr_src,
                                                   const int* __restrict__ rowptr,
                                                   const float* __restrict__ rout,
                                                   const float* __restrict__ cbuf,
                                                   const float* __restrict__ b3,
                                                   float* __restrict__ out, int nN)
{
    const int gid = blockIdx.x * 256 + threadIdx.x;
    const int node = gid >> 3;
    const int j = gid & 7;
    if (node >= nN) return;
    const int beg = rowptr[node], end = rowptr[node + 1];
    const bool isch = (j < 5);
    float a[8];
#pragma unroll
    for (int k = 0; k < 8; ++k) a[k] = 0.f;

    for (int e = beg; e < end; e += 8) {
        int s[8];
#pragma unroll
        for (int b = 0; b < 8; ++b) {
            const int idx = e + b;
            s[b] = csr_src[idx < end ? idx : end - 1];
        }
        if (isch) {
            uint4 u[8];
#pragma unroll
            for (int b = 0; b < 8; ++b)
                u[b] = ((const uint4*)(qbuf + (size_t)s[b] * 40))[j];
#pragma unroll
            for (int b = 0; b < 8; ++b) {
                if (e + b < end) {
                    float2 f;
                    f = unpack2(u[b].x); a[0] += f.x; a[1] += f.y;
                    f = unpack2(u[b].y); a[2] += f.x; a[3] += f.y;
                    f = unpack2(u[b].z); a[4] += f.x; a[5] += f.y;
                    f = unpack2(u[b].w); a[6] += f.x; a[7] += f.y;
                }
            }
        }
    }

    const float ro = rout[node];
    const float c  = cbuf[node];
    float z[8];
    float m = -1e30f, ssum = 0.f;
    if (isch) {
#pragma unroll
        for (int k = 0; k < 8; ++k) {
            z[k] = ro * a[k] + c * b3[j * 8 + k];
            m = fmaxf(m, z[k]);
        }
    }
    m = fmaxf(m, __shfl_xor(m, 1));
    m = fmaxf(m, __shfl_xor(m, 2));
    m = fmaxf(m, __shfl_xor(m, 4));
    if (isch) {
#pragma unroll
        for (int k = 0; k < 8; ++k) { z[k] = __expf(z[k] - m); ssum += z[k]; }
    }
    ssum += __shfl_xor(ssum, 1);
    ssum += __shfl_xor(ssum, 2);
    ssum += __shfl_xor(ssum, 4);
    if (isch) {
        const float inv = 1.f / ssum;
        float4* orow = (float4*)(out + (size_t)node * 40);
        orow[j * 2 + 0] = make_float4(z[0] * inv, z[1] * inv, z[2] * inv, z[3] * inv);
        orow[j * 2 + 1] = make_float4(z[4] * inv, z[5] * inv, z[6] * inv, z[7] * inv);
    }
}

extern "C" void kernel_launch(void* const* d_in, const int* in_sizes, int n_in,
                              void* d_out, int out_size, void* d_ws, size_t ws_size,
                              hipStream_t stream)
{
    const float* nodes = (const float*)d_in[0];
    const int*   snd   = (const int*)d_in[1];
    const int*   rcv   = (const int*)d_in[2];
    const float* W1    = (const float*)d_in[3];
    const float* b1    = (const float*)d_in[4];
    const float* W2    = (const float*)d_in[5];
    const float* b2    = (const float*)d_in[6];
    const float* W3    = (const float*)d_in[7];
    const float* b3    = (const float*)d_in[8];

    const int nN = in_sizes[0] / 128;
    const int nE = in_sizes[1];
    const int NR = (nN + RANGE - 1) >> RANGE_BITS;   // 4 for N=100000
    const int NS = (nE + SLICE - 1) >> SLICE_BITS;   // 25 for E=1.6M

    size_t off = 0;
    auto alloc = [&](size_t n) { size_t r = off; off += (n + 3) & ~(size_t)3; return r; };
    int*   dr_i    = (int*)d_ws + alloc(nN);
    int*   rowptr  = (int*)d_ws + alloc(nN + 1);
    int*   bsums   = (int*)d_ws + alloc(256);
    float* rin     = (float*)d_ws + alloc(nN);
    float* rout    = (float*)d_ws + alloc(nN);
    float* cbuf    = (float*)d_ws + alloc(nN);
    int*   csr_src = (int*)d_ws + alloc(nE);
    // union region: {partial(u32) + pos16(u16)} (dead after fill) overlaps {pbuf + qbuf} (fp16)
    const size_t psz = (size_t)2 * NR * NS * HWORDS;            // words
    size_t ubase = alloc(0);
    unsigned*       partial = (unsigned*)d_ws + ubase;
    unsigned short* pos16   = (unsigned short*)((unsigned*)d_ws + ubase + psz);
    __half* pbuf = (__half*)((int*)d_ws + ubase);
    __half* qbuf = pbuf + (size_t)nN * 40;     // byte offset nN*80, 16B-aligned

    const int nb1 = (nN + 1023) / 1024;

    count_kernel<<<2 * NR * NS, 1024, 0, stream>>>(snd, rcv, partial, pos16, nE, NR, NS);
    scanp_kernel<<<(NR * HWORDS + 255) / 256, 256, 0, stream>>>(partial, dr_i, rin, rout, nN, NR, NS);
    scan1_kernel<<<nb1, 256, 0, stream>>>(dr_i, rowptr, bsums, nN);
    scan2_kernel<<<1, 256, 0, stream>>>(bsums, nb1);
    scan3_kernel<<<(nN + 255) / 256, 256, 0, stream>>>(rowptr, bsums, nN, nE);
    fill_kernel<<<(nE + 255) / 256, 256, 0, stream>>>(snd, rcv, pos16, partial, rowptr, csr_src, nE, NS);
    mlp_kernel<<<(nN + 63) / 64, 256, 0, stream>>>(nodes, W1, b1, W2, b2, W3, rin, pbuf, nN);
    agg1_kernel<<<((size_t)nN * 8 + 255) / 256, 256, 0, stream>>>(pbuf, csr_src, rowptr, rin, rout, qbuf, cbuf, nN);
    agg2_kernel<<<((size_t)nN * 8 + 255) / 256, 256, 0, stream>>>(qbuf, csr_src, rowptr, rout, cbuf, b3, (float*)d_out, nN);
}